// Round 2
// baseline (1573.367 us; speedup 1.0000x reference)
//
#include <hip/hip_runtime.h>
#include <hip/hip_bf16.h>

// CrissCrossAttentionBlock: B=8, H=W=96, C=512, c=64. N = 73728 pixels.
// External tensors are fp32 (per reference). Internals: q,k,S fp32; v,yv bf16.
//
// Pipeline:
//  1) proj_gemm x3: q = x@Wq+bq (Nx64 f32), k = x@Wk+bk (Nx64 f32),
//                   v = x@Wv+bv (Nx512 bf16)
//  2) cc_scores: S[n][0:96] = vertical scores (diag -1e30), [96:192] horizontal
//  3) cc_softmax: per-pixel softmax over 192 logits (in place, fp32)
//  4) cc_aggr_v: yv[n] = sum_g A[n][g] * v[col g]   (bf16 out)
//  5) cc_aggr_h_final: out = (yv + yh)*gamma + x    (fp32 out)

#define NPIX 73728
#define HH 96
#define WW 96
#define CC 512
#define CQ 64

__device__ __forceinline__ void load8_bf16(const __hip_bfloat16* p, float* dst) {
    const uint4 u = *reinterpret_cast<const uint4*>(p);
    unsigned int w0 = u.x, w1 = u.y, w2 = u.z, w3 = u.w;
    dst[0] = __uint_as_float((w0 & 0xffffu) << 16);
    dst[1] = __uint_as_float(w0 & 0xffff0000u);
    dst[2] = __uint_as_float((w1 & 0xffffu) << 16);
    dst[3] = __uint_as_float(w1 & 0xffff0000u);
    dst[4] = __uint_as_float((w2 & 0xffffu) << 16);
    dst[5] = __uint_as_float(w2 & 0xffff0000u);
    dst[6] = __uint_as_float((w3 & 0xffffu) << 16);
    dst[7] = __uint_as_float(w3 & 0xffff0000u);
}

__device__ __forceinline__ void storeOut(float* p, float v) { *p = v; }
__device__ __forceinline__ void storeOut(__hip_bfloat16* p, float v) { *p = __float2bfloat16(v); }

// ---------------------------------------------------------------------------
// 1) Projection GEMM: out[n][j] = sum_c X[n][c]*W[c][j] + bias[j]
//    Tiles: BM=64, BN=64, BK=32; 256 threads; 4x4 micro-tile per thread.
// ---------------------------------------------------------------------------
template <typename OutT>
__global__ __launch_bounds__(256) void proj_gemm(
    const float* __restrict__ X,     // N x 512
    const float* __restrict__ W,     // 512 x J
    const float* __restrict__ bias,  // J
    OutT* __restrict__ out,          // N x J
    int J)
{
    __shared__ float Xs[64][33];
    __shared__ float Ws[32][65];
    const int tid = threadIdx.x;
    const int mBase = blockIdx.x * 64;
    const int nBase = blockIdx.y * 64;
    const int tx = tid & 15, ty = tid >> 4;

    float acc[4][4] = {};

    for (int kb = 0; kb < 512; kb += 32) {
        {   // X tile: 64 rows x 32 cols; 8 floats (two float4) per thread
            int row = tid >> 2;
            int col = (tid & 3) * 8;
            const float* src = X + (size_t)(mBase + row) * 512 + kb + col;
            float4 a = *reinterpret_cast<const float4*>(src);
            float4 b = *reinterpret_cast<const float4*>(src + 4);
            Xs[row][col + 0] = a.x; Xs[row][col + 1] = a.y;
            Xs[row][col + 2] = a.z; Xs[row][col + 3] = a.w;
            Xs[row][col + 4] = b.x; Xs[row][col + 5] = b.y;
            Xs[row][col + 6] = b.z; Xs[row][col + 7] = b.w;
        }
        {   // W tile: 32 rows x 64 cols
            int row = tid >> 3;
            int col = (tid & 7) * 8;
            const float* src = W + (size_t)(kb + row) * J + nBase + col;
            float4 a = *reinterpret_cast<const float4*>(src);
            float4 b = *reinterpret_cast<const float4*>(src + 4);
            Ws[row][col + 0] = a.x; Ws[row][col + 1] = a.y;
            Ws[row][col + 2] = a.z; Ws[row][col + 3] = a.w;
            Ws[row][col + 4] = b.x; Ws[row][col + 5] = b.y;
            Ws[row][col + 6] = b.z; Ws[row][col + 7] = b.w;
        }
        __syncthreads();
        #pragma unroll
        for (int kk = 0; kk < 32; ++kk) {
            float a[4], b[4];
            #pragma unroll
            for (int i = 0; i < 4; ++i) a[i] = Xs[ty * 4 + i][kk];
            #pragma unroll
            for (int j = 0; j < 4; ++j) b[j] = Ws[kk][tx * 4 + j];
            #pragma unroll
            for (int i = 0; i < 4; ++i)
                #pragma unroll
                for (int j = 0; j < 4; ++j)
                    acc[i][j] += a[i] * b[j];
        }
        __syncthreads();
    }

    float bj[4];
    #pragma unroll
    for (int j = 0; j < 4; ++j) bj[j] = bias[nBase + tx * 4 + j];
    #pragma unroll
    for (int i = 0; i < 4; ++i) {
        size_t rowOff = (size_t)(mBase + ty * 4 + i) * J + nBase + tx * 4;
        #pragma unroll
        for (int j = 0; j < 4; ++j)
            storeOut(&out[rowOff + j], acc[i][j] + bj[j]);
    }
}

// ---------------------------------------------------------------------------
// 2) Scores. blockIdx.y==0: vertical (per (b,w) column), ==1: horizontal (per
//    (b,h) row). Stage 96x64 Q,K tiles in LDS, compute 96x96 dot products.
// ---------------------------------------------------------------------------
__global__ __launch_bounds__(256) void cc_scores(
    const float* __restrict__ Q,     // N x 64
    const float* __restrict__ K,     // N x 64
    float* __restrict__ S)           // N x 192
{
    __shared__ float Qs[96][65];
    __shared__ float Ks[96][65];
    const int tid = threadIdx.x;
    const bool vert = (blockIdx.y == 0);
    const int b = blockIdx.x / 96;
    const int line = blockIdx.x % 96;   // w (vert) or h (horiz)

    size_t base;     // pixel index of row 0
    int rowStride;   // pixel stride between rows
    if (vert) { base = (size_t)b * (96 * 96) + line;  rowStride = 96; }
    else      { base = ((size_t)b * 96 + line) * 96;  rowStride = 1;  }

    // 96 rows x 16 float4-quads per matrix = 1536 units; 6 iters @ 256 thr
    for (int idx = tid; idx < 1536; idx += 256) {
        int row = idx >> 4;
        int c4 = (idx & 15) * 4;
        size_t goff = (base + (size_t)row * rowStride) * CQ + c4;
        float4 tq = *reinterpret_cast<const float4*>(Q + goff);
        Qs[row][c4 + 0] = tq.x; Qs[row][c4 + 1] = tq.y;
        Qs[row][c4 + 2] = tq.z; Qs[row][c4 + 3] = tq.w;
        float4 tk = *reinterpret_cast<const float4*>(K + goff);
        Ks[row][c4 + 0] = tk.x; Ks[row][c4 + 1] = tk.y;
        Ks[row][c4 + 2] = tk.z; Ks[row][c4 + 3] = tk.w;
    }
    __syncthreads();

    for (int p = tid; p < 96 * 96; p += 256) {
        int i = p / 96;
        int j = p - i * 96;
        float acc = 0.f;
        #pragma unroll 8
        for (int c = 0; c < CQ; ++c) acc += Qs[i][c] * Ks[j][c];
        size_t n = base + (size_t)i * rowStride;
        float val = (vert && i == j) ? -1e30f : acc;
        S[n * 192 + (vert ? j : 96 + j)] = val;
    }
}

// ---------------------------------------------------------------------------
// 3) Softmax over 192 logits per pixel. One wave (64 lanes) per pixel.
// ---------------------------------------------------------------------------
__global__ __launch_bounds__(256) void cc_softmax(float* __restrict__ S)
{
    const int tid = threadIdx.x;
    const int lane = tid & 63;
    const size_t n = (size_t)blockIdx.x * 4 + (tid >> 6);
    float* row = S + n * 192;
    float s0 = row[lane], s1 = row[lane + 64], s2 = row[lane + 128];
    float m = fmaxf(s0, fmaxf(s1, s2));
    #pragma unroll
    for (int off = 32; off >= 1; off >>= 1) m = fmaxf(m, __shfl_xor(m, off, 64));
    float e0 = expf(s0 - m), e1 = expf(s1 - m), e2 = expf(s2 - m);
    float sum = e0 + e1 + e2;
    #pragma unroll
    for (int off = 32; off >= 1; off >>= 1) sum += __shfl_xor(sum, off, 64);
    float inv = 1.0f / sum;
    row[lane] = e0 * inv;
    row[lane + 64] = e1 * inv;
    row[lane + 128] = e2 * inv;
}

// ---------------------------------------------------------------------------
// 4) Vertical aggregation: per (b,w) column, Yv[h][c] = sum_g A[h][g]*V[g][c].
//    blockIdx.y selects a 64-wide channel slab. 6x4 outputs per thread.
// ---------------------------------------------------------------------------
__global__ __launch_bounds__(256) void cc_aggr_v(
    const float* __restrict__ A,             // N x 192 (cols 0..95 used)
    const __hip_bfloat16* __restrict__ V,    // N x 512
    __hip_bfloat16* __restrict__ Yv)         // N x 512
{
    __shared__ float As[96][97];
    __shared__ float Vs[96][64];
    const int tid = threadIdx.x;
    const int b = blockIdx.x / 96;
    const int w = blockIdx.x % 96;
    const int cBase = blockIdx.y * 64;

    for (int idx = tid; idx < 96 * 96; idx += 256) {
        int h = idx / 96, g = idx - h * 96;
        As[h][g] = A[((size_t)(b * 96 + h) * 96 + w) * 192 + g];
    }
    for (int chunk = tid; chunk < 768; chunk += 256) {
        int g = chunk >> 3, cc = (chunk & 7) * 8;
        float tmp[8];
        load8_bf16(V + ((size_t)(b * 96 + g) * 96 + w) * 512 + cBase + cc, tmp);
        #pragma unroll
        for (int q = 0; q < 8; ++q) Vs[g][cc + q] = tmp[q];
    }
    __syncthreads();

    const int tx = tid & 15, ty = tid >> 4;
    const int h0 = ty * 6, c0 = tx * 4;
    float acc[6][4] = {};
    for (int g = 0; g < 96; ++g) {
        float vb[4];
        #pragma unroll
        for (int j = 0; j < 4; ++j) vb[j] = Vs[g][c0 + j];
        #pragma unroll
        for (int i = 0; i < 6; ++i) {
            float a = As[h0 + i][g];
            #pragma unroll
            for (int j = 0; j < 4; ++j) acc[i][j] += a * vb[j];
        }
    }
    #pragma unroll
    for (int i = 0; i < 6; ++i) {
        size_t off = ((size_t)(b * 96 + h0 + i) * 96 + w) * 512 + cBase + c0;
        #pragma unroll
        for (int j = 0; j < 4; ++j) Yv[off + j] = __float2bfloat16(acc[i][j]);
    }
}

// ---------------------------------------------------------------------------
// 5) Horizontal aggregation + epilogue: per (b,h) row,
//    out = (Yv + Yh)*gamma + x   (fp32 out)
// ---------------------------------------------------------------------------
__global__ __launch_bounds__(256) void cc_aggr_h_final(
    const float* __restrict__ A,             // N x 192 (cols 96..191 used)
    const __hip_bfloat16* __restrict__ V,    // N x 512
    const __hip_bfloat16* __restrict__ Yv,   // N x 512
    const float* __restrict__ X,             // N x 512
    const float* __restrict__ gamma_p,
    float* __restrict__ out)                 // N x 512
{
    __shared__ float As[96][97];
    __shared__ float Vs[96][64];
    const int tid = threadIdx.x;
    const int b = blockIdx.x / 96;
    const int h = blockIdx.x % 96;
    const int cBase = blockIdx.y * 64;
    const size_t rowBase = (size_t)(b * 96 + h) * 96;   // pixel index of (b,h,0)

    for (int idx = tid; idx < 96 * 96; idx += 256) {
        int wq = idx / 96, u = idx - wq * 96;
        As[wq][u] = A[(rowBase + wq) * 192 + 96 + u];
    }
    for (int chunk = tid; chunk < 768; chunk += 256) {
        int u = chunk >> 3, cc = (chunk & 7) * 8;
        float tmp[8];
        load8_bf16(V + (rowBase + u) * 512 + cBase + cc, tmp);
        #pragma unroll
        for (int q = 0; q < 8; ++q) Vs[u][cc + q] = tmp[q];
    }
    __syncthreads();

    const int tx = tid & 15, ty = tid >> 4;
    const int w0 = ty * 6, c0 = tx * 4;
    float acc[6][4] = {};
    for (int u = 0; u < 96; ++u) {
        float vb[4];
        #pragma unroll
        for (int j = 0; j < 4; ++j) vb[j] = Vs[u][c0 + j];
        #pragma unroll
        for (int i = 0; i < 6; ++i) {
            float a = As[w0 + i][u];
            #pragma unroll
            for (int j = 0; j < 4; ++j) acc[i][j] += a * vb[j];
        }
    }

    const float gm = gamma_p[0];
    #pragma unroll
    for (int i = 0; i < 6; ++i) {
        size_t off = (rowBase + w0 + i) * 512 + cBase + c0;
        #pragma unroll
        for (int j = 0; j < 4; ++j) {
            float val = (acc[i][j] + __bfloat162float(Yv[off + j])) * gm + X[off + j];
            out[off + j] = val;
        }
    }
}

// ---------------------------------------------------------------------------
extern "C" void kernel_launch(void* const* d_in, const int* in_sizes, int n_in,
                              void* d_out, int out_size, void* d_ws, size_t ws_size,
                              hipStream_t stream) {
    const float* x     = (const float*)d_in[0];
    const float* Wq    = (const float*)d_in[1];
    const float* bq    = (const float*)d_in[2];
    const float* Wk    = (const float*)d_in[3];
    const float* bk    = (const float*)d_in[4];
    const float* Wv    = (const float*)d_in[5];
    const float* bv    = (const float*)d_in[6];
    const float* gamma = (const float*)d_in[7];
    float* out = (float*)d_out;

    // Workspace layout (bytes):
    //   q  : NPIX*64*4  = 18,874,368  (fp32)
    //   k  : NPIX*64*4  = 18,874,368  (fp32)
    //   v  : NPIX*512*2 = 75,497,472  (bf16)
    //   S  : NPIX*192*4 = 56,623,104  (fp32)
    //   yv : NPIX*512*2 = 75,497,472  (bf16)   total ~234 MiB
    char* ws = (char*)d_ws;
    float*          q  = (float*)ws;
    float*          k  = q + (size_t)NPIX * CQ;
    __hip_bfloat16* v  = (__hip_bfloat16*)(k + (size_t)NPIX * CQ);
    float*          S  = (float*)(v + (size_t)NPIX * CC);
    __hip_bfloat16* yv = (__hip_bfloat16*)(S + (size_t)NPIX * 192);

    proj_gemm<float><<<dim3(NPIX / 64, 1), 256, 0, stream>>>(x, Wq, bq, q, CQ);
    proj_gemm<float><<<dim3(NPIX / 64, 1), 256, 0, stream>>>(x, Wk, bk, k, CQ);
    proj_gemm<__hip_bfloat16><<<dim3(NPIX / 64, 8), 256, 0, stream>>>(x, Wv, bv, v, CC);

    cc_scores<<<dim3(8 * 96, 2), 256, 0, stream>>>(q, k, S);
    cc_softmax<<<NPIX / 4, 256, 0, stream>>>(S);

    cc_aggr_v<<<dim3(8 * 96, 8), 256, 0, stream>>>(S, v, yv);
    cc_aggr_h_final<<<dim3(8 * 96, 8), 256, 0, stream>>>(S, v, yv, x, gamma, out);
}

// Round 3
// 870.174 us; speedup vs baseline: 1.8081x; 1.8081x over previous
//
#include <hip/hip_runtime.h>
#include <hip/hip_bf16.h>

// CrissCrossAttentionBlock: B=8, H=W=96, C=512, c=64. N = 73728 pixels.
// External tensors fp32. Internals: xb,q,k,v,yv bf16; S fp32.
//
// Pipeline:
//  0) conv_x: x fp32 -> xb bf16 (row-major); conv_w x3: W fp32 -> fragment-major bf16
//  1) mfma_proj x3: q,k (Nx64 bf16), v (Nx512 bf16) via 16x16x32 bf16 MFMA
//  2) cc_scores: S[n][0:96] vertical (diag -1e30), [96:192] horizontal (fp32)
//  3) cc_softmax: per-pixel softmax over 192 logits
//  4) cc_aggr_v: yv = Av @ V (bf16; yv aliases xb)
//  5) cc_aggr_h_final: out = (yv + yh)*gamma + x (fp32)

#define NPIX 73728
#define HH 96
#define WW 96
#define CC 512
#define CQ 64

typedef __attribute__((ext_vector_type(8))) short bf16x8;
typedef __attribute__((ext_vector_type(4))) float f32x4;

__device__ __forceinline__ void async16(const void* g, void* l) {
    __builtin_amdgcn_global_load_lds(
        (const __attribute__((address_space(1))) unsigned int*)g,
        (__attribute__((address_space(3))) unsigned int*)l,
        16, 0, 0);
}

__device__ __forceinline__ void load8_bf16(const __hip_bfloat16* p, float* dst) {
    const uint4 u = *reinterpret_cast<const uint4*>(p);
    unsigned int w0 = u.x, w1 = u.y, w2 = u.z, w3 = u.w;
    dst[0] = __uint_as_float((w0 & 0xffffu) << 16);
    dst[1] = __uint_as_float(w0 & 0xffff0000u);
    dst[2] = __uint_as_float((w1 & 0xffffu) << 16);
    dst[3] = __uint_as_float(w1 & 0xffff0000u);
    dst[4] = __uint_as_float((w2 & 0xffffu) << 16);
    dst[5] = __uint_as_float(w2 & 0xffff0000u);
    dst[6] = __uint_as_float((w3 & 0xffffu) << 16);
    dst[7] = __uint_as_float(w3 & 0xffff0000u);
}

// ---------------------------------------------------------------------------
// 0a) x fp32 -> bf16, row-major. 8 elems per thread.
// ---------------------------------------------------------------------------
__global__ __launch_bounds__(256) void conv_x(
    const float* __restrict__ x, short* __restrict__ xb)
{
    size_t i8 = ((size_t)blockIdx.x * 256 + threadIdx.x) * 8;
    float4 a = *reinterpret_cast<const float4*>(x + i8);
    float4 b = *reinterpret_cast<const float4*>(x + i8 + 4);
    union { __hip_bfloat16 h[8]; uint4 u; } pk;
    pk.h[0] = __float2bfloat16(a.x); pk.h[1] = __float2bfloat16(a.y);
    pk.h[2] = __float2bfloat16(a.z); pk.h[3] = __float2bfloat16(a.w);
    pk.h[4] = __float2bfloat16(b.x); pk.h[5] = __float2bfloat16(b.y);
    pk.h[6] = __float2bfloat16(b.z); pk.h[7] = __float2bfloat16(b.w);
    *reinterpret_cast<uint4*>(xb + i8) = pk.u;
}

// ---------------------------------------------------------------------------
// 0b) W (512 x J fp32, row-major) -> B-fragment-major bf16:
//     dst[((kb32*(J/16)+ntile)*64 + lane)*8 + j] =
//        W[kb32*32 + (lane>>4)*8 + j][ntile*16 + (lane&15)]
// ---------------------------------------------------------------------------
__global__ __launch_bounds__(256) void conv_w(
    const float* __restrict__ W, short* __restrict__ dst, int J)
{
    int idx = blockIdx.x * 256 + threadIdx.x;   // one 8-elem fragment per thread
    int lane = idx & 63;
    int blk = idx >> 6;
    int ntiles = J >> 4;
    int ntile = blk % ntiles;
    int kb32 = blk / ntiles;
    int krow = kb32 * 32 + (lane >> 4) * 8;
    int col = ntile * 16 + (lane & 15);
    union { __hip_bfloat16 h[8]; uint4 u; } pk;
    #pragma unroll
    for (int j = 0; j < 8; ++j)
        pk.h[j] = __float2bfloat16(W[(size_t)(krow + j) * J + col]);
    *reinterpret_cast<uint4*>(dst + (size_t)idx * 8) = pk.u;
}

// ---------------------------------------------------------------------------
// 1) MFMA projection GEMM: out[n][j] = xb[n][:] @ W[:][j] + bias[j]
//    Tile 128 x BN, BK=32, 256 threads (4 waves).
//    BN=128: waves 2x2, each 64x64 (MT=4,NT=4). BN=64: waves 4x1, each 32x64.
//    A staged fragment-major in LDS via global_load_lds(16B);
//    B-frags read straight from fragment-major global (L2-resident).
// ---------------------------------------------------------------------------
template <int BN>
__global__ __launch_bounds__(256) void mfma_proj(
    const short* __restrict__ Xb,    // N x 512 bf16
    const short* __restrict__ Wf,    // fragment-major bf16
    const float* __restrict__ bias,  // J fp32
    short* __restrict__ out,         // N x J bf16
    int J)
{
    __shared__ __align__(16) short Albuf[128 * 32];   // fragment-major, 8 KB
    const int tid = threadIdx.x;
    const int lane = tid & 63;
    const int w = tid >> 6;
    const int mBase = blockIdx.x * 128;
    const int nBase = blockIdx.y * BN;

    constexpr int MT = (BN == 128) ? 4 : 2;
    constexpr int NT = 4;
    const int wr = (BN == 128) ? (w >> 1) : w;
    const int wc = (BN == 128) ? (w & 1) : 0;
    const int tbase = wr * MT;
    const int nTile0 = (nBase >> 4) + wc * 4;
    const int ntilesJ = J >> 4;

    f32x4 acc[MT][NT];
    #pragma unroll
    for (int i = 0; i < MT; ++i)
        #pragma unroll
        for (int j = 0; j < NT; ++j) {
            f32x4 z = {0.f, 0.f, 0.f, 0.f};
            acc[i][j] = z;
        }

    const int arow0 = lane & 15;        // m within tile
    const int acol0 = (lane >> 4) * 8;  // k within 32

    for (int kb = 0; kb < 16; ++kb) {
        #pragma unroll
        for (int s = 0; s < 2; ++s) {
            int t = w * 2 + s;
            const short* g = Xb + (size_t)(mBase + t * 16 + arow0) * 512 + kb * 32 + acol0;
            async16(g, &Albuf[t * 512]);
        }
        __syncthreads();

        bf16x8 bf[NT];
        #pragma unroll
        for (int jn = 0; jn < NT; ++jn)
            bf[jn] = *reinterpret_cast<const bf16x8*>(
                Wf + ((size_t)(kb * ntilesJ + nTile0 + jn) * 64 + lane) * 8);
        bf16x8 af[MT];
        #pragma unroll
        for (int i = 0; i < MT; ++i)
            af[i] = *reinterpret_cast<const bf16x8*>(&Albuf[(tbase + i) * 512 + lane * 8]);
        #pragma unroll
        for (int i = 0; i < MT; ++i)
            #pragma unroll
            for (int jn = 0; jn < NT; ++jn)
                acc[i][jn] = __builtin_amdgcn_mfma_f32_16x16x32_bf16(
                    af[i], bf[jn], acc[i][jn], 0, 0, 0);
        __syncthreads();
    }

    // Epilogue: D[row=(lane>>4)*4+r][col=lane&15] per 16x16 tile.
    const int lrow = (lane >> 4) * 4, lcol = lane & 15;
    #pragma unroll
    for (int jn = 0; jn < NT; ++jn) {
        int col = nBase + wc * 64 + jn * 16 + lcol;
        float bc = bias[col];
        #pragma unroll
        for (int i = 0; i < MT; ++i) {
            int row = mBase + wr * (MT * 16) + i * 16 + lrow;
            #pragma unroll
            for (int r = 0; r < 4; ++r) {
                __hip_bfloat16 hb = __float2bfloat16(acc[i][jn][r] + bc);
                out[(size_t)(row + r) * J + col] = *reinterpret_cast<short*>(&hb);
            }
        }
    }
}

// ---------------------------------------------------------------------------
// 2) Scores. blockIdx.y==0: vertical (per (b,w) column), ==1: horizontal.
// ---------------------------------------------------------------------------
__global__ __launch_bounds__(256) void cc_scores(
    const __hip_bfloat16* __restrict__ Q,   // N x 64 bf16
    const __hip_bfloat16* __restrict__ K,   // N x 64 bf16
    float* __restrict__ S)                  // N x 192
{
    __shared__ float Qs[96][65];
    __shared__ float Ks[96][65];
    const int tid = threadIdx.x;
    const bool vert = (blockIdx.y == 0);
    const int b = blockIdx.x / 96;
    const int line = blockIdx.x % 96;

    size_t base;
    int rowStride;
    if (vert) { base = (size_t)b * (96 * 96) + line;  rowStride = 96; }
    else      { base = ((size_t)b * 96 + line) * 96;  rowStride = 1;  }

    for (int chunk = tid; chunk < 768; chunk += 256) {
        int row = chunk >> 3;
        int cc = (chunk & 7) * 8;
        size_t goff = (base + (size_t)row * rowStride) * CQ + cc;
        float tmp[8];
        load8_bf16(Q + goff, tmp);
        #pragma unroll
        for (int q = 0; q < 8; ++q) Qs[row][cc + q] = tmp[q];
        load8_bf16(K + goff, tmp);
        #pragma unroll
        for (int q = 0; q < 8; ++q) Ks[row][cc + q] = tmp[q];
    }
    __syncthreads();

    for (int p = tid; p < 96 * 96; p += 256) {
        int i = p / 96;
        int j = p - i * 96;
        float acc = 0.f;
        #pragma unroll 8
        for (int c = 0; c < CQ; ++c) acc += Qs[i][c] * Ks[j][c];
        size_t n = base + (size_t)i * rowStride;
        float val = (vert && i == j) ? -1e30f : acc;
        S[n * 192 + (vert ? j : 96 + j)] = val;
    }
}

// ---------------------------------------------------------------------------
// 3) Softmax over 192 logits per pixel. One wave per pixel.
// ---------------------------------------------------------------------------
__global__ __launch_bounds__(256) void cc_softmax(float* __restrict__ S)
{
    const int tid = threadIdx.x;
    const int lane = tid & 63;
    const size_t n = (size_t)blockIdx.x * 4 + (tid >> 6);
    float* row = S + n * 192;
    float s0 = row[lane], s1 = row[lane + 64], s2 = row[lane + 128];
    float m = fmaxf(s0, fmaxf(s1, s2));
    #pragma unroll
    for (int off = 32; off >= 1; off >>= 1) m = fmaxf(m, __shfl_xor(m, off, 64));
    float e0 = expf(s0 - m), e1 = expf(s1 - m), e2 = expf(s2 - m);
    float sum = e0 + e1 + e2;
    #pragma unroll
    for (int off = 32; off >= 1; off >>= 1) sum += __shfl_xor(sum, off, 64);
    float inv = 1.0f / sum;
    row[lane] = e0 * inv;
    row[lane + 64] = e1 * inv;
    row[lane + 128] = e2 * inv;
}

// ---------------------------------------------------------------------------
// 4) Vertical aggregation: per (b,w) column, Yv[h][c] = sum_g A[h][g]*V[g][c].
// ---------------------------------------------------------------------------
__global__ __launch_bounds__(256) void cc_aggr_v(
    const float* __restrict__ A,             // N x 192 (cols 0..95)
    const __hip_bfloat16* __restrict__ V,    // N x 512
    __hip_bfloat16* __restrict__ Yv)         // N x 512
{
    __shared__ float As[96][97];
    __shared__ float Vs[96][64];
    const int tid = threadIdx.x;
    const int b = blockIdx.x / 96;
    const int w = blockIdx.x % 96;
    const int cBase = blockIdx.y * 64;

    for (int idx = tid; idx < 96 * 96; idx += 256) {
        int h = idx / 96, g = idx - h * 96;
        As[h][g] = A[((size_t)(b * 96 + h) * 96 + w) * 192 + g];
    }
    for (int chunk = tid; chunk < 768; chunk += 256) {
        int g = chunk >> 3, cc = (chunk & 7) * 8;
        float tmp[8];
        load8_bf16(V + ((size_t)(b * 96 + g) * 96 + w) * 512 + cBase + cc, tmp);
        #pragma unroll
        for (int q = 0; q < 8; ++q) Vs[g][cc + q] = tmp[q];
    }
    __syncthreads();

    const int tx = tid & 15, ty = tid >> 4;
    const int h0 = ty * 6, c0 = tx * 4;
    float acc[6][4] = {};
    for (int g = 0; g < 96; ++g) {
        float vb[4];
        #pragma unroll
        for (int j = 0; j < 4; ++j) vb[j] = Vs[g][c0 + j];
        #pragma unroll
        for (int i = 0; i < 6; ++i) {
            float a = As[h0 + i][g];
            #pragma unroll
            for (int j = 0; j < 4; ++j) acc[i][j] += a * vb[j];
        }
    }
    #pragma unroll
    for (int i = 0; i < 6; ++i) {
        size_t off = ((size_t)(b * 96 + h0 + i) * 96 + w) * 512 + cBase + c0;
        #pragma unroll
        for (int j = 0; j < 4; ++j) Yv[off + j] = __float2bfloat16(acc[i][j]);
    }
}

// ---------------------------------------------------------------------------
// 5) Horizontal aggregation + epilogue: out = (Yv + Yh)*gamma + x (fp32)
// ---------------------------------------------------------------------------
__global__ __launch_bounds__(256) void cc_aggr_h_final(
    const float* __restrict__ A,             // N x 192 (cols 96..191)
    const __hip_bfloat16* __restrict__ V,    // N x 512
    const __hip_bfloat16* __restrict__ Yv,   // N x 512
    const float* __restrict__ X,             // N x 512
    const float* __restrict__ gamma_p,
    float* __restrict__ out)                 // N x 512
{
    __shared__ float As[96][97];
    __shared__ float Vs[96][64];
    const int tid = threadIdx.x;
    const int b = blockIdx.x / 96;
    const int h = blockIdx.x % 96;
    const int cBase = blockIdx.y * 64;
    const size_t rowBase = (size_t)(b * 96 + h) * 96;

    for (int idx = tid; idx < 96 * 96; idx += 256) {
        int wq = idx / 96, u = idx - wq * 96;
        As[wq][u] = A[(rowBase + wq) * 192 + 96 + u];
    }
    for (int chunk = tid; chunk < 768; chunk += 256) {
        int u = chunk >> 3, cc = (chunk & 7) * 8;
        float tmp[8];
        load8_bf16(V + (rowBase + u) * 512 + cBase + cc, tmp);
        #pragma unroll
        for (int q = 0; q < 8; ++q) Vs[u][cc + q] = tmp[q];
    }
    __syncthreads();

    const int tx = tid & 15, ty = tid >> 4;
    const int w0 = ty * 6, c0 = tx * 4;
    float acc[6][4] = {};
    for (int u = 0; u < 96; ++u) {
        float vb[4];
        #pragma unroll
        for (int j = 0; j < 4; ++j) vb[j] = Vs[u][c0 + j];
        #pragma unroll
        for (int i = 0; i < 6; ++i) {
            float a = As[w0 + i][u];
            #pragma unroll
            for (int j = 0; j < 4; ++j) acc[i][j] += a * vb[j];
        }
    }

    const float gm = gamma_p[0];
    #pragma unroll
    for (int i = 0; i < 6; ++i) {
        size_t off = (rowBase + w0 + i) * 512 + cBase + c0;
        #pragma unroll
        for (int j = 0; j < 4; ++j) {
            float val = (acc[i][j] + __bfloat162float(Yv[off + j])) * gm + X[off + j];
            out[off + j] = val;
        }
    }
}

// ---------------------------------------------------------------------------
extern "C" void kernel_launch(void* const* d_in, const int* in_sizes, int n_in,
                              void* d_out, int out_size, void* d_ws, size_t ws_size,
                              hipStream_t stream) {
    const float* x     = (const float*)d_in[0];
    const float* Wq    = (const float*)d_in[1];
    const float* bq    = (const float*)d_in[2];
    const float* Wk    = (const float*)d_in[3];
    const float* bk    = (const float*)d_in[4];
    const float* Wv    = (const float*)d_in[5];
    const float* bv    = (const float*)d_in[6];
    const float* gamma = (const float*)d_in[7];
    float* out = (float*)d_out;

    // Workspace (shorts unless noted); yv aliases xb (dead after projections).
    //   xb  : NPIX*512            = 37,748,736
    //   Wqf : 512*64              =     32,768
    //   Wkf : 512*64              =     32,768
    //   Wvf : 512*512             =    262,144
    //   q,k : NPIX*64 each        =  4,718,592 x2
    //   v   : NPIX*512            = 37,748,736
    //   S   : NPIX*192 fp32       (after v)        total ~217 MiB
    short* xb  = (short*)d_ws;
    short* Wqf = xb + (size_t)NPIX * 512;
    short* Wkf = Wqf + 512 * 64;
    short* Wvf = Wkf + 512 * 64;
    short* q   = Wvf + 512 * 512;
    short* k   = q + (size_t)NPIX * CQ;
    short* v   = k + (size_t)NPIX * CQ;
    float* S   = (float*)(v + (size_t)NPIX * CC);
    __hip_bfloat16* yv = (__hip_bfloat16*)xb;   // alias

    conv_x<<<NPIX * 512 / 8 / 256, 256, 0, stream>>>(x, xb);
    conv_w<<<16, 256, 0, stream>>>(Wq, Wqf, 64);
    conv_w<<<16, 256, 0, stream>>>(Wk, Wkf, 64);
    conv_w<<<128, 256, 0, stream>>>(Wv, Wvf, 512);

    mfma_proj<64><<<dim3(NPIX / 128, 1), 256, 0, stream>>>(xb, Wqf, bq, q, CQ);
    mfma_proj<64><<<dim3(NPIX / 128, 1), 256, 0, stream>>>(xb, Wkf, bk, k, CQ);
    mfma_proj<128><<<dim3(NPIX / 128, 4), 256, 0, stream>>>(xb, Wvf, bv, v, CC);

    cc_scores<<<dim3(8 * 96, 2), 256, 0, stream>>>(
        (const __hip_bfloat16*)q, (const __hip_bfloat16*)k, S);
    cc_softmax<<<NPIX / 4, 256, 0, stream>>>(S);

    cc_aggr_v<<<dim3(8 * 96, 8), 256, 0, stream>>>(S, (const __hip_bfloat16*)v, yv);
    cc_aggr_h_final<<<dim3(8 * 96, 8), 256, 0, stream>>>(
        S, (const __hip_bfloat16*)v, yv, x, gamma, out);
}